// Round 1
// baseline (1253.726 us; speedup 1.0000x reference)
//
#include <hip/hip_runtime.h>
#include <math.h>

#define NHW   9216     // 96*96
#define NROWS 36864    // NHW*4

__device__ __forceinline__ float softplusf(float x) {
    return fmaxf(x, 0.f) + log1pf(expf(-fabsf(x)));
}

// ---------------- positional encoding ctx[hw][128] ----------------
__global__ __launch_bounds__(256) void ctx_kernel(float* __restrict__ ctx) {
    int e = blockIdx.x * 256 + threadIdx.x;
    if (e >= NHW * 128) return;
    int c  = e & 127;
    int hw = e >> 7;
    int i = hw / 96, j = hw % 96;
    int pos = (c < 64) ? i : j;
    int cc = c & 63;
    int k = cc >> 1;
    float invf = powf(10000.f, -(float)k / 32.f);
    float v = (float)pos * invf;
    ctx[e] = (cc & 1) ? cosf(v) : sinf(v);
}

// ---------------- spatial_norm -> z[row][16], row = (i*96+j)*4+b ----------------
__global__ __launch_bounds__(256) void snorm_kernel(const float* __restrict__ x,
                                                    float* __restrict__ z) {
    int e = blockIdx.x * 256 + threadIdx.x;
    if (e >= NROWS * 16) return;
    int j = e % 96;
    int i = (e / 96) % 96;
    int s = (e / 9216) % 16;
    int b = e / (9216 * 16);
    float sum = 0.f;
    const float* xb = x + (size_t)((b * 16 + s) * 3) * 192 * 192;
    #pragma unroll
    for (int c = 0; c < 3; ++c) {
        const float* xc = xb + (size_t)c * 192 * 192;
        #pragma unroll
        for (int dh = -1; dh <= 1; ++dh) {
            int hh = 2 * i + dh;
            if (hh < 0 || hh >= 192) continue;
            const float* xr = xc + hh * 192;
            #pragma unroll
            for (int dw = -1; dw <= 1; ++dw) {
                int ww = 2 * j + dw;
                if (ww < 0 || ww >= 192) continue;
                float v = xr[ww];
                sum += v * v;
            }
        }
    }
    int row = (i * 96 + j) * 4 + b;
    z[(size_t)row * 16 + s] = sqrtf(sum);
}

// ---------------- init logq with sum of LU log-dets (constant) ----------------
__global__ __launch_bounds__(256) void initlogq_kernel(const float* __restrict__ lu_udiag,
                                                       float* __restrict__ logq) {
    int row = blockIdx.x * 256 + threadIdx.x;
    if (row >= NROWS) return;
    float c0 = 0.f;
    for (int k = 0; k < 64; ++k)
        c0 += logf(softplusf(lu_udiag[k]) + 0.001f);
    logq[row] = c0;
}

// ---------------- LU transform: z = L(U z_perm) + bias (in place per row) ----------------
__global__ __launch_bounds__(256) void lu_kernel(float* __restrict__ z,
                                                 const float* __restrict__ lower,
                                                 const float* __restrict__ upper,
                                                 const float* __restrict__ udiag_raw,
                                                 const float* __restrict__ bias,
                                                 const int* __restrict__ perm) {
    int row = blockIdx.x * 256 + threadIdx.x;
    if (row >= NROWS) return;
    float* zr = z + (size_t)row * 16;
    float zp[16], y[16];
    #pragma unroll
    for (int d = 0; d < 16; ++d) zp[d] = zr[perm[d]];
    #pragma unroll
    for (int r = 0; r < 16; ++r) {
        float acc = (softplusf(udiag_raw[r]) + 0.001f) * zp[r];
        #pragma unroll
        for (int c = 0; c < 16; ++c)
            if (c > r) acc += upper[r * 16 + c] * zp[c];
        y[r] = acc;
    }
    #pragma unroll
    for (int r = 0; r < 16; ++r) {
        float acc = y[r] + bias[r];
        #pragma unroll
        for (int c = 0; c < 16; ++c)
            if (c < r) acc += lower[r * 16 + c] * y[c];
        zr[r] = acc;
    }
}

// ---------------- tiled f32 GEMM: C[M,N] = post(preA(A[M,K]) @ W[N,K]^T + bias) ------------
// PRE: 0 none, 1 relu on A. POST: 0 store, 1 sigmoid, 2 silu, 3 C += val*gate[(m>>2)*128+n].
// MASK on W: 0 none, 1 MASK_HID ((n%15)>=(k%15)), 2 MASK_OUT ((n%16)>(k%15)).
template<int PRE, int POST, int MASK>
__global__ __launch_bounds__(256) void gemm_k(
    const float* __restrict__ A, int lda,
    const float* __restrict__ W, int ldw,
    const float* __restrict__ bias,
    const float* __restrict__ gate,
    float* __restrict__ C, int ldc,
    int M, int N, int K)
{
    __shared__ alignas(16) float As[16][68];
    __shared__ alignas(16) float Ws[16][68];
    const int tid = threadIdx.x;
    const int m0 = blockIdx.x * 64;
    const int n0 = blockIdx.y * 64;
    const int tm = (tid >> 4) << 2;
    const int tn = (tid & 15) << 2;
    const int srow = tid >> 2;
    const int skq  = (tid & 3) << 2;

    float acc[4][4] = {{0.f, 0.f, 0.f, 0.f}, {0.f, 0.f, 0.f, 0.f},
                       {0.f, 0.f, 0.f, 0.f}, {0.f, 0.f, 0.f, 0.f}};

    for (int k0 = 0; k0 < K; k0 += 16) {
        float4 av = *(const float4*)(A + (size_t)(m0 + srow) * lda + k0 + skq);
        if (PRE == 1) {
            av.x = fmaxf(av.x, 0.f); av.y = fmaxf(av.y, 0.f);
            av.z = fmaxf(av.z, 0.f); av.w = fmaxf(av.w, 0.f);
        }
        As[skq + 0][srow] = av.x; As[skq + 1][srow] = av.y;
        As[skq + 2][srow] = av.z; As[skq + 3][srow] = av.w;

        int wn = n0 + srow;
        float4 wv = make_float4(0.f, 0.f, 0.f, 0.f);
        if (wn < N) {
            wv = *(const float4*)(W + (size_t)wn * ldw + k0 + skq);
            if (MASK == 1) {
                int nm = wn % 15;
                if (nm < ((k0 + skq + 0) % 15)) wv.x = 0.f;
                if (nm < ((k0 + skq + 1) % 15)) wv.y = 0.f;
                if (nm < ((k0 + skq + 2) % 15)) wv.z = 0.f;
                if (nm < ((k0 + skq + 3) % 15)) wv.w = 0.f;
            } else if (MASK == 2) {
                int nm = wn & 15;
                if (nm <= ((k0 + skq + 0) % 15)) wv.x = 0.f;
                if (nm <= ((k0 + skq + 1) % 15)) wv.y = 0.f;
                if (nm <= ((k0 + skq + 2) % 15)) wv.z = 0.f;
                if (nm <= ((k0 + skq + 3) % 15)) wv.w = 0.f;
            }
        }
        Ws[skq + 0][srow] = wv.x; Ws[skq + 1][srow] = wv.y;
        Ws[skq + 2][srow] = wv.z; Ws[skq + 3][srow] = wv.w;
        __syncthreads();
        #pragma unroll
        for (int kk = 0; kk < 16; ++kk) {
            float4 a4 = *(const float4*)&As[kk][tm];
            float4 w4 = *(const float4*)&Ws[kk][tn];
            float aa[4] = {a4.x, a4.y, a4.z, a4.w};
            float wwv[4] = {w4.x, w4.y, w4.z, w4.w};
            #pragma unroll
            for (int q = 0; q < 4; ++q)
                #pragma unroll
                for (int r = 0; r < 4; ++r)
                    acc[q][r] = fmaf(aa[q], wwv[r], acc[q][r]);
        }
        __syncthreads();
    }
    #pragma unroll
    for (int q = 0; q < 4; ++q) {
        int m = m0 + tm + q;
        #pragma unroll
        for (int r = 0; r < 4; ++r) {
            int n = n0 + tn + r;
            if (n < N) {
                float val = acc[q][r] + bias[n];
                float* cp = C + (size_t)m * ldc + n;
                if (POST == 0)      *cp = val;
                else if (POST == 1) *cp = 1.f / (1.f + expf(-val));
                else if (POST == 2) *cp = val / (1.f + expf(-val));
                else                *cp += val * gate[(size_t)(m >> 2) * 128 + n];
            }
        }
    }
}

// ---------------- t[row][h] = thw[hw][h] + zid[row] @ WinZ^T (flow input layer) ----------
__global__ __launch_bounds__(256) void expand_flow_kernel(const float* __restrict__ thw,
                                                          const float* __restrict__ z,
                                                          const float* __restrict__ win,
                                                          float* __restrict__ t) {
    int e = blockIdx.x * 256 + threadIdx.x;
    if (e >= NROWS * 128) return;
    int h = e & 127;
    int row = e >> 7;
    float acc = thw[(size_t)(row >> 2) * 128 + h];
    const float* zr = z + (size_t)row * 16;
    const float* wr = win + (size_t)h * 136;
    #pragma unroll
    for (int d = 0; d < 8; ++d) acc += zr[2 * d] * wr[d];
    t[e] = acc;
}

// ---------------- MADE input layer: masked W0 + b0 ----------------
__global__ __launch_bounds__(256) void expand_made_kernel(const float* __restrict__ thw,
                                                          const float* __restrict__ z,
                                                          const float* __restrict__ w0,
                                                          const float* __restrict__ b0,
                                                          float* __restrict__ t) {
    int e = blockIdx.x * 256 + threadIdx.x;
    if (e >= NROWS * 128) return;
    int h = e & 127;
    int row = e >> 7;
    float acc = thw[(size_t)(row >> 2) * 128 + h] + b0[h];
    const float* zr = z + (size_t)row * 16;
    const float* wr = w0 + (size_t)h * 16;
    int hm = h % 15;
    #pragma unroll
    for (int d = 0; d < 16; ++d)
        if (hm >= d) acc += zr[d] * wr[d];
    t[e] = acc;
}

// ---------------- rational-quadratic spline ----------------
__device__ __forceinline__ void knots8(const float* __restrict__ u, float* c, float* w) {
    float mx = u[0];
    #pragma unroll
    for (int k = 1; k < 8; ++k) mx = fmaxf(mx, u[k]);
    float e[8]; float s = 0.f;
    #pragma unroll
    for (int k = 0; k < 8; ++k) { e[k] = expf(u[k] - mx); s += e[k]; }
    float inv = 1.f / s;
    c[0] = -3.f;
    float cum = 0.f;
    #pragma unroll
    for (int k = 0; k < 8; ++k) {
        float v = 0.001f + 0.992f * e[k] * inv;
        cum += v;
        c[k + 1] = cum * 6.f - 3.f;
    }
    c[8] = 3.f;
    #pragma unroll
    for (int k = 0; k < 8; ++k) w[k] = c[k + 1] - c[k];
}

__device__ __forceinline__ void rqs1(float x,
                                     const float* __restrict__ uw,
                                     const float* __restrict__ uh,
                                     const float* __restrict__ ud,
                                     float& y, float& ld) {
    float cw[9], wd[8], ch[9], hg[8], dd[9];
    knots8(uw, cw, wd);
    knots8(uh, ch, hg);
    dd[0] = 1.f; dd[8] = 1.f;
    #pragma unroll
    for (int k = 0; k < 7; ++k) dd[k + 1] = 0.001f + softplusf(ud[k]);
    bool inside = (x >= -3.f) && (x <= 3.f);
    float xc = fminf(fmaxf(x, -3.f), 3.f);
    // select bin: last k in [0,7] with xc >= cw[k] (scan keeps everything in registers)
    float cwk = cw[0], wk = wd[0], chk = ch[0], hk = hg[0], d0 = dd[0], d1 = dd[1];
    #pragma unroll
    for (int k = 1; k < 8; ++k) {
        if (xc >= cw[k]) { cwk = cw[k]; wk = wd[k]; chk = ch[k]; hk = hg[k]; d0 = dd[k]; d1 = dd[k + 1]; }
    }
    float dl = hk / wk;
    float th = (xc - cwk) / wk;
    float t1 = th * (1.f - th);
    float den = dl + (d0 + d1 - 2.f * dl) * t1;
    float yy = chk + hk * (dl * th * th + d0 * t1) / den;
    float om = 1.f - th;
    float dnum = dl * dl * (d1 * th * th + 2.f * dl * t1 + d0 * om * om);
    float lld = logf(dnum) - 2.f * logf(den);
    y  = inside ? yy : x;
    ld = inside ? lld : 0.f;
}

__global__ __launch_bounds__(256) void spline_kernel(float* __restrict__ z,
                                                     const float* __restrict__ p,
                                                     const float* __restrict__ uw_id,
                                                     const float* __restrict__ uh_id,
                                                     const float* __restrict__ ud_id,
                                                     float* __restrict__ logq) {
    int e = blockIdx.x * 256 + threadIdx.x;
    if (e >= NROWS * 8) return;
    int dim = e & 7;
    int row = e >> 3;
    float zid = z[(size_t)row * 16 + 2 * dim];
    float ztr = z[(size_t)row * 16 + 2 * dim + 1];
    const float* pr = p + (size_t)row * 184 + dim * 23;
    const float inv_sqrt_h = 0.08838834764831845f;  // 1/sqrt(128)
    float uw[8], uh[8], ud[7];
    #pragma unroll
    for (int k = 0; k < 8; ++k) { uw[k] = pr[k] * inv_sqrt_h; uh[k] = pr[8 + k] * inv_sqrt_h; }
    #pragma unroll
    for (int k = 0; k < 7; ++k) ud[k] = pr[16 + k];
    float ytr, ldtr; rqs1(ztr, uw, uh, ud, ytr, ldtr);
    float yid, ldid; rqs1(zid, uw_id + dim * 8, uh_id + dim * 8, ud_id + dim * 7, yid, ldid);
    z[(size_t)row * 16 + 2 * dim]     = yid;
    z[(size_t)row * 16 + 2 * dim + 1] = ytr;
    float ld = ldtr + ldid;
    ld += __shfl_xor(ld, 1);
    ld += __shfl_xor(ld, 2);
    ld += __shfl_xor(ld, 4);
    if (dim == 0) logq[row] += ld;
}

// ---------------- MADE output: scale/shift z, accumulate log|scale| ----------------
__global__ __launch_bounds__(256) void made_out_kernel(const float* __restrict__ ar,
                                                       float* __restrict__ z,
                                                       float* __restrict__ logq) {
    int row = blockIdx.x * 256 + threadIdx.x;
    if (row >= NROWS) return;
    const float* a = ar + (size_t)row * 32;
    float* zr = z + (size_t)row * 16;
    float lacc = 0.f;
    #pragma unroll
    for (int d = 0; d < 16; ++d) {
        float s = softplusf(a[2 * d]) + 0.001f;
        zr[d] = s * zr[d] + a[2 * d + 1];
        lacc += logf(s);
    }
    logq[row] += lacc;
}

// ---------------- Gaussian head + output transpose ----------------
__global__ __launch_bounds__(256) void final_kernel(const float* __restrict__ z,
                                                    const float* __restrict__ ehw,
                                                    const float* __restrict__ logq,
                                                    float* __restrict__ out) {
    int row = blockIdx.x * 256 + threadIdx.x;
    if (row >= NROWS) return;
    int hw = row >> 2, b = row & 3;
    const float* e = ehw + (size_t)hw * 32;
    const float* zr = z + (size_t)row * 16;
    float lq = logq[row] - 14.703016531274762f;  // -0.5*16*log(2*pi)
    #pragma unroll
    for (int d = 0; d < 16; ++d) {
        float ls = e[16 + d];
        float diff = (zr[d] - e[d]) * expf(-ls);
        lq -= ls + 0.5f * diff * diff;
    }
    out[(size_t)b * NHW + hw] = lq;
}

extern "C" void kernel_launch(void* const* d_in, const int* in_sizes, int n_in,
                              void* d_out, int out_size, void* d_ws, size_t ws_size,
                              hipStream_t stream) {
    (void)in_sizes; (void)n_in; (void)out_size; (void)ws_size;
    const float* x         = (const float*)d_in[0];
    const float* made_W0   = (const float*)d_in[1];
    const float* made_b0   = (const float*)d_in[2];
    const float* made_ctxW = (const float*)d_in[3];
    const float* made_ctxb = (const float*)d_in[4];
    const float* made_bW1  = (const float*)d_in[5];
    const float* made_bb1  = (const float*)d_in[6];
    const float* made_bW2  = (const float*)d_in[7];
    const float* made_bb2  = (const float*)d_in[8];
    const float* made_bCW  = (const float*)d_in[9];
    const float* made_bCb  = (const float*)d_in[10];
    const float* made_Wout = (const float*)d_in[11];
    const float* made_bout = (const float*)d_in[12];
    const float* sp_Win    = (const float*)d_in[13];
    const float* sp_bin    = (const float*)d_in[14];
    const float* sp_bW1    = (const float*)d_in[15];
    const float* sp_bb1    = (const float*)d_in[16];
    const float* sp_bW2    = (const float*)d_in[17];
    const float* sp_bb2    = (const float*)d_in[18];
    const float* sp_bCW    = (const float*)d_in[19];
    const float* sp_bCb    = (const float*)d_in[20];
    const float* sp_Wout   = (const float*)d_in[21];
    const float* sp_bout   = (const float*)d_in[22];
    const float* sp_uw     = (const float*)d_in[23];
    const float* sp_uh     = (const float*)d_in[24];
    const float* sp_ud     = (const float*)d_in[25];
    const float* lu_lower  = (const float*)d_in[26];
    const float* lu_upper  = (const float*)d_in[27];
    const float* lu_udiag  = (const float*)d_in[28];
    const float* lu_bias   = (const float*)d_in[29];
    const int*   lu_perm   = (const int*)d_in[30];
    const float* enc_W1    = (const float*)d_in[31];
    const float* enc_b1    = (const float*)d_in[32];
    const float* enc_W2    = (const float*)d_in[33];
    const float* enc_b2    = (const float*)d_in[34];
    float* out = (float*)d_out;

    // workspace layout (floats): ~87.4 MB total
    float* ws   = (float*)d_ws;
    float* ctx  = ws;                            // 9216*128
    float* thw  = ctx + (size_t)NHW * 128;       // 9216*128 (also encoder hidden)
    float* g1   = thw + (size_t)NHW * 128;       // 9216*128
    float* g2   = g1 + (size_t)NHW * 128;        // 9216*128
    float* z    = g2 + (size_t)NHW * 128;        // 36864*16
    float* logq = z + (size_t)NROWS * 16;        // 36864
    float* t    = logq + NROWS;                  // 36864*128
    float* u    = t + (size_t)NROWS * 128;       // 36864*128
    float* p    = u + (size_t)NROWS * 128;       // 36864*184 (also MADE ar 36864*32)
    float* ehw  = p + (size_t)NROWS * 184;       // 9216*32

    dim3 B(256);
    ctx_kernel<<<4608, B, 0, stream>>>(ctx);
    snorm_kernel<<<2304, B, 0, stream>>>(x, z);
    initlogq_kernel<<<144, B, 0, stream>>>(lu_udiag, logq);

    for (int i = 3; i >= 0; --i) {
        lu_kernel<<<144, B, 0, stream>>>(z, lu_lower + i * 256, lu_upper + i * 256,
                                         lu_udiag + i * 16, lu_bias + i * 16, lu_perm + i * 16);
        // thw = ctx @ WinCtx^T + bin   (Win columns 8..135)
        gemm_k<0,0,0><<<dim3(144, 2), B, 0, stream>>>(ctx, 128, sp_Win + (size_t)i * 17408 + 8, 136,
                                                      sp_bin + i * 128, nullptr, thw, 128, NHW, 128, 128);
        gemm_k<0,1,0><<<dim3(144, 2), B, 0, stream>>>(ctx, 128, sp_bCW + (size_t)(i * 2 + 0) * 16384, 128,
                                                      sp_bCb + (i * 2 + 0) * 128, nullptr, g1, 128, NHW, 128, 128);
        gemm_k<0,1,0><<<dim3(144, 2), B, 0, stream>>>(ctx, 128, sp_bCW + (size_t)(i * 2 + 1) * 16384, 128,
                                                      sp_bCb + (i * 2 + 1) * 128, nullptr, g2, 128, NHW, 128, 128);
        expand_flow_kernel<<<18432, B, 0, stream>>>(thw, z, sp_Win + (size_t)i * 17408, t);
        for (int blk = 0; blk < 2; ++blk) {
            const float* gate = blk ? g2 : g1;
            gemm_k<1,0,0><<<dim3(576, 2), B, 0, stream>>>(t, 128, sp_bW1 + (size_t)(i * 2 + blk) * 16384, 128,
                                                          sp_bb1 + (i * 2 + blk) * 128, nullptr, u, 128, NROWS, 128, 128);
            gemm_k<1,3,0><<<dim3(576, 2), B, 0, stream>>>(u, 128, sp_bW2 + (size_t)(i * 2 + blk) * 16384, 128,
                                                          sp_bb2 + (i * 2 + blk) * 128, gate, t, 128, NROWS, 128, 128);
        }
        gemm_k<0,0,0><<<dim3(576, 3), B, 0, stream>>>(t, 128, sp_Wout + (size_t)i * 23552, 128,
                                                      sp_bout + i * 184, nullptr, p, 184, NROWS, 184, 128);
        spline_kernel<<<1152, B, 0, stream>>>(z, p, sp_uw + i * 64, sp_uh + i * 64, sp_ud + i * 56, logq);
    }

    // ---- MADE ----
    gemm_k<0,0,0><<<dim3(144, 2), B, 0, stream>>>(ctx, 128, made_ctxW, 128, made_ctxb, nullptr, thw, 128, NHW, 128, 128);
    gemm_k<0,1,0><<<dim3(144, 2), B, 0, stream>>>(ctx, 128, made_bCW, 128, made_bCb, nullptr, g1, 128, NHW, 128, 128);
    gemm_k<0,1,0><<<dim3(144, 2), B, 0, stream>>>(ctx, 128, made_bCW + 16384, 128, made_bCb + 128, nullptr, g2, 128, NHW, 128, 128);
    expand_made_kernel<<<18432, B, 0, stream>>>(thw, z, made_W0, made_b0, t);
    for (int blk = 0; blk < 2; ++blk) {
        const float* gate = blk ? g2 : g1;
        gemm_k<1,0,1><<<dim3(576, 2), B, 0, stream>>>(t, 128, made_bW1 + (size_t)blk * 16384, 128,
                                                      made_bb1 + blk * 128, nullptr, u, 128, NROWS, 128, 128);
        gemm_k<1,3,1><<<dim3(576, 2), B, 0, stream>>>(u, 128, made_bW2 + (size_t)blk * 16384, 128,
                                                      made_bb2 + blk * 128, gate, t, 128, NROWS, 128, 128);
    }
    gemm_k<0,0,2><<<dim3(576, 1), B, 0, stream>>>(t, 128, made_Wout, 128, made_bout, nullptr, p, 32, NROWS, 32, 128);
    made_out_kernel<<<144, B, 0, stream>>>(p, z, logq);

    // ---- encoder (per-hw) ----
    gemm_k<0,2,0><<<dim3(144, 2), B, 0, stream>>>(ctx, 128, enc_W1, 128, enc_b1, nullptr, thw, 128, NHW, 128, 128);
    gemm_k<0,0,0><<<dim3(144, 1), B, 0, stream>>>(thw, 128, enc_W2, 128, enc_b2, nullptr, ehw, 32, NHW, 32, 128);
    final_kernel<<<144, B, 0, stream>>>(z, ehw, logq, out);
}

// Round 3
// 975.384 us; speedup vs baseline: 1.2854x; 1.2854x over previous
//
#include <hip/hip_runtime.h>
#include <math.h>

#define NHW   9216     // 96*96
#define NROWS 36864    // NHW*4

__device__ __forceinline__ float softplusf(float x) {
    return fmaxf(x, 0.f) + log1pf(expf(-fabsf(x)));
}

// ---------------- positional encoding ctx[hw][128] ----------------
__global__ __launch_bounds__(256) void ctx_kernel(float* __restrict__ ctx) {
    int e = blockIdx.x * 256 + threadIdx.x;
    if (e >= NHW * 128) return;
    int c  = e & 127;
    int hw = e >> 7;
    int i = hw / 96, j = hw % 96;
    int pos = (c < 64) ? i : j;
    int cc = c & 63;
    int k = cc >> 1;
    float invf = powf(10000.f, -(float)k / 32.f);
    float v = (float)pos * invf;
    ctx[e] = (cc & 1) ? cosf(v) : sinf(v);
}

// ---------------- spatial_norm -> z[row][16], row = (i*96+j)*4+b ----------------
__global__ __launch_bounds__(256) void snorm_kernel(const float* __restrict__ x,
                                                    float* __restrict__ z) {
    int e = blockIdx.x * 256 + threadIdx.x;
    if (e >= NROWS * 16) return;
    int j = e % 96;
    int i = (e / 96) % 96;
    int s = (e / 9216) % 16;
    int b = e / (9216 * 16);
    float sum = 0.f;
    const float* xb = x + (size_t)((b * 16 + s) * 3) * 192 * 192;
    #pragma unroll
    for (int c = 0; c < 3; ++c) {
        const float* xc = xb + (size_t)c * 192 * 192;
        #pragma unroll
        for (int dh = -1; dh <= 1; ++dh) {
            int hh = 2 * i + dh;
            if (hh < 0 || hh >= 192) continue;
            const float* xr = xc + hh * 192;
            #pragma unroll
            for (int dw = -1; dw <= 1; ++dw) {
                int ww = 2 * j + dw;
                if (ww < 0 || ww >= 192) continue;
                float v = xr[ww];
                sum += v * v;
            }
        }
    }
    int row = (i * 96 + j) * 4 + b;
    z[(size_t)row * 16 + s] = sqrtf(sum);
}

// ---------------- init logq with sum of LU log-dets (constant) ----------------
__global__ __launch_bounds__(256) void initlogq_kernel(const float* __restrict__ lu_udiag,
                                                       float* __restrict__ logq) {
    int row = blockIdx.x * 256 + threadIdx.x;
    if (row >= NROWS) return;
    float c0 = 0.f;
    for (int k = 0; k < 64; ++k)
        c0 += logf(softplusf(lu_udiag[k]) + 0.001f);
    logq[row] = c0;
}

// ---------------- LU transform: z = L(U z_perm) + bias (in place per row) ----------------
__global__ __launch_bounds__(256) void lu_kernel(float* __restrict__ z,
                                                 const float* __restrict__ lower,
                                                 const float* __restrict__ upper,
                                                 const float* __restrict__ udiag_raw,
                                                 const float* __restrict__ bias,
                                                 const int* __restrict__ perm) {
    int row = blockIdx.x * 256 + threadIdx.x;
    if (row >= NROWS) return;
    float* zr = z + (size_t)row * 16;
    float zp[16], y[16];
    #pragma unroll
    for (int d = 0; d < 16; ++d) zp[d] = zr[perm[d]];
    #pragma unroll
    for (int r = 0; r < 16; ++r) {
        float acc = (softplusf(udiag_raw[r]) + 0.001f) * zp[r];
        #pragma unroll
        for (int c = 0; c < 16; ++c)
            if (c > r) acc += upper[r * 16 + c] * zp[c];
        y[r] = acc;
    }
    #pragma unroll
    for (int r = 0; r < 16; ++r) {
        float acc = y[r] + bias[r];
        #pragma unroll
        for (int c = 0; c < 16; ++c)
            if (c < r) acc += lower[r * 16 + c] * y[c];
        zr[r] = acc;
    }
}

// ---------------- one-time weight pack/transpose kernel ----------------
// cat 0: fWT1[8][128][128]  = T(sp_bW1)
// cat 1: fWT2               = T(sp_bW2)
// cat 2: mWT1[2][128][128]  = T(made_bW1 * MASK_HID)
// cat 3: mWT2               = T(made_bW2 * MASK_HID)
// cat 4: fWoutT[4][128][184]= T(sp_Wout)
// cat 5: mWoutT[128][32]    = T(made_Wout * MASK_OUT)
// cat 6: fwinzT[4][8][128]  = T(sp_Win[:, :, 0:8])
// cat 7: mW0T[16][128]      = T(made_W0 * MASK_IN)
// cat 8: fpw[4][384][128]   = rows {Win_ctx, bCW0, bCW1}
// cat 9: mpw[384][128]      = rows {made_ctxW, made_bCW0, made_bCW1}
// cat 10: fpb[4][384], cat 11: mpb[384]
__global__ __launch_bounds__(256) void pack_kernel(
    const float* __restrict__ sp_bW1, const float* __restrict__ sp_bW2,
    const float* __restrict__ made_bW1, const float* __restrict__ made_bW2,
    const float* __restrict__ sp_Wout, const float* __restrict__ made_Wout,
    const float* __restrict__ sp_Win, const float* __restrict__ made_W0,
    const float* __restrict__ sp_bCW, const float* __restrict__ made_ctxW,
    const float* __restrict__ made_bCW,
    const float* __restrict__ sp_bin, const float* __restrict__ sp_bCb,
    const float* __restrict__ made_ctxb, const float* __restrict__ made_b0,
    const float* __restrict__ made_bCb,
    float* __restrict__ fWT1, float* __restrict__ fWT2,
    float* __restrict__ mWT1, float* __restrict__ mWT2,
    float* __restrict__ fWoutT, float* __restrict__ mWoutT,
    float* __restrict__ fwinzT, float* __restrict__ mW0T,
    float* __restrict__ fpw, float* __restrict__ mpw,
    float* __restrict__ fpb, float* __restrict__ mpb)
{
    int cat = blockIdx.y;
    int e = blockIdx.x * 256 + threadIdx.x;
    switch (cat) {
    case 0: if (e < 8 * 16384) {
        int mtx = e >> 14, k = (e >> 7) & 127, n = e & 127;
        fWT1[e] = sp_bW1[mtx * 16384 + n * 128 + k];
    } break;
    case 1: if (e < 8 * 16384) {
        int mtx = e >> 14, k = (e >> 7) & 127, n = e & 127;
        fWT2[e] = sp_bW2[mtx * 16384 + n * 128 + k];
    } break;
    case 2: if (e < 2 * 16384) {
        int mtx = e >> 14, k = (e >> 7) & 127, n = e & 127;
        mWT1[e] = ((n % 15) >= (k % 15)) ? made_bW1[mtx * 16384 + n * 128 + k] : 0.f;
    } break;
    case 3: if (e < 2 * 16384) {
        int mtx = e >> 14, k = (e >> 7) & 127, n = e & 127;
        mWT2[e] = ((n % 15) >= (k % 15)) ? made_bW2[mtx * 16384 + n * 128 + k] : 0.f;
    } break;
    case 4: if (e < 4 * 23552) {
        int s = e / 23552, r = e % 23552, k = r / 184, n = r % 184;
        fWoutT[e] = sp_Wout[s * 23552 + n * 128 + k];
    } break;
    case 5: if (e < 4096) {
        int k = e >> 5, n = e & 31;
        mWoutT[e] = ((n & 15) > (k % 15)) ? made_Wout[n * 128 + k] : 0.f;
    } break;
    case 6: if (e < 4 * 1024) {
        int s = e >> 10, r = e & 1023, d = r >> 7, h = r & 127;
        fwinzT[e] = sp_Win[s * 17408 + h * 136 + d];
    } break;
    case 7: if (e < 2048) {
        int d = e >> 7, h = e & 127;
        mW0T[e] = ((h % 15) >= d) ? made_W0[h * 16 + d] : 0.f;
    } break;
    case 8: if (e < 4 * 49152) {
        int s = e / 49152, r = e % 49152, n = r >> 7, k = r & 127;
        float v;
        if (n < 128)      v = sp_Win[s * 17408 + n * 136 + 8 + k];
        else if (n < 256) v = sp_bCW[(size_t)(s * 2 + 0) * 16384 + (n - 128) * 128 + k];
        else              v = sp_bCW[(size_t)(s * 2 + 1) * 16384 + (n - 256) * 128 + k];
        fpw[e] = v;
    } break;
    case 9: if (e < 49152) {
        int n = e >> 7, k = e & 127;
        float v;
        if (n < 128)      v = made_ctxW[n * 128 + k];
        else if (n < 256) v = made_bCW[(n - 128) * 128 + k];
        else              v = made_bCW[16384 + (n - 256) * 128 + k];
        mpw[e] = v;
    } break;
    case 10: if (e < 4 * 384) {
        int s = e / 384, n = e % 384;
        float v;
        if (n < 128)      v = sp_bin[s * 128 + n];
        else if (n < 256) v = sp_bCb[(s * 2 + 0) * 128 + (n - 128)];
        else              v = sp_bCb[(s * 2 + 1) * 128 + (n - 256)];
        fpb[e] = v;
    } break;
    case 11: if (e < 384) {
        float v;
        if (e < 128)      v = made_ctxb[e] + made_b0[e];
        else if (e < 256) v = made_bCb[e - 128];
        else              v = made_bCb[128 + (e - 256)];
        mpb[e] = v;
    } break;
    }
}

// ---------------- tiled f32 GEMM (ctx / encoder): C = post(A @ W^T + bias) ----------------
// POST: 0 store, 2 silu, 4 mixed (n<128 store, else sigmoid)
template<int POST>
__global__ __launch_bounds__(256) void gemm_k(
    const float* __restrict__ A, int lda,
    const float* __restrict__ W, int ldw,
    const float* __restrict__ bias,
    float* __restrict__ C, int ldc,
    int M, int N, int K)
{
    __shared__ alignas(16) float As[16][68];
    __shared__ alignas(16) float Ws[16][68];
    const int tid = threadIdx.x;
    const int m0 = blockIdx.x * 64;
    const int n0 = blockIdx.y * 64;
    const int tm = (tid >> 4) << 2;
    const int tn = (tid & 15) << 2;
    const int srow = tid >> 2;
    const int skq  = (tid & 3) << 2;

    float acc[4][4] = {{0.f,0.f,0.f,0.f},{0.f,0.f,0.f,0.f},{0.f,0.f,0.f,0.f},{0.f,0.f,0.f,0.f}};

    for (int k0 = 0; k0 < K; k0 += 16) {
        float4 av = *(const float4*)(A + (size_t)(m0 + srow) * lda + k0 + skq);
        As[skq + 0][srow] = av.x; As[skq + 1][srow] = av.y;
        As[skq + 2][srow] = av.z; As[skq + 3][srow] = av.w;
        int wn = n0 + srow;
        float4 wv = make_float4(0.f, 0.f, 0.f, 0.f);
        if (wn < N) wv = *(const float4*)(W + (size_t)wn * ldw + k0 + skq);
        Ws[skq + 0][srow] = wv.x; Ws[skq + 1][srow] = wv.y;
        Ws[skq + 2][srow] = wv.z; Ws[skq + 3][srow] = wv.w;
        __syncthreads();
        #pragma unroll
        for (int kk = 0; kk < 16; ++kk) {
            float4 a4 = *(const float4*)&As[kk][tm];
            float4 w4 = *(const float4*)&Ws[kk][tn];
            float aa[4] = {a4.x, a4.y, a4.z, a4.w};
            float wwv[4] = {w4.x, w4.y, w4.z, w4.w};
            #pragma unroll
            for (int q = 0; q < 4; ++q)
                #pragma unroll
                for (int r = 0; r < 4; ++r)
                    acc[q][r] = fmaf(aa[q], wwv[r], acc[q][r]);
        }
        __syncthreads();
    }
    #pragma unroll
    for (int q = 0; q < 4; ++q) {
        int m = m0 + tm + q;
        #pragma unroll
        for (int r = 0; r < 4; ++r) {
            int n = n0 + tn + r;
            if (n < N) {
                float val = acc[q][r] + bias[n];
                float* cp = C + (size_t)m * ldc + n;
                if (POST == 0)      *cp = val;
                else if (POST == 2) *cp = val / (1.f + expf(-val));
                else                *cp = (n < 128) ? val : 1.f / (1.f + expf(-val));
            }
        }
    }
}

// ---------------- fused per-flow-step mega kernel ----------------
// block = 256 threads, 32 rows. LDS-resident t/u. Weights pre-transposed (k-major).
template<bool RELU>
__device__ __forceinline__ void tile_gemm128(const float (*__restrict__ src)[132],
                                             const float* __restrict__ WT,
                                             int rowg, int colg, float acc[4][4]) {
    #pragma unroll
    for (int q = 0; q < 4; ++q)
        #pragma unroll
        for (int r = 0; r < 4; ++r)
            acc[q][r] = 0.f;
    for (int k = 0; k < 128; k += 4) {
        float4 w0 = *(const float4*)(WT + (k + 0) * 128 + colg * 4);
        float4 w1 = *(const float4*)(WT + (k + 1) * 128 + colg * 4);
        float4 w2 = *(const float4*)(WT + (k + 2) * 128 + colg * 4);
        float4 w3 = *(const float4*)(WT + (k + 3) * 128 + colg * 4);
        #pragma unroll
        for (int q = 0; q < 4; ++q) {
            float4 av = *(const float4*)&src[rowg * 4 + q][k];
            float a0 = RELU ? fmaxf(av.x, 0.f) : av.x;
            float a1 = RELU ? fmaxf(av.y, 0.f) : av.y;
            float a2 = RELU ? fmaxf(av.z, 0.f) : av.z;
            float a3 = RELU ? fmaxf(av.w, 0.f) : av.w;
            acc[q][0] = fmaf(a3, w3.x, fmaf(a2, w2.x, fmaf(a1, w1.x, fmaf(a0, w0.x, acc[q][0]))));
            acc[q][1] = fmaf(a3, w3.y, fmaf(a2, w2.y, fmaf(a1, w1.y, fmaf(a0, w0.y, acc[q][1]))));
            acc[q][2] = fmaf(a3, w3.z, fmaf(a2, w2.z, fmaf(a1, w1.z, fmaf(a0, w0.z, acc[q][2]))));
            acc[q][3] = fmaf(a3, w3.w, fmaf(a2, w2.w, fmaf(a1, w1.w, fmaf(a0, w0.w, acc[q][3]))));
        }
    }
}

template<int MODE>   // 0 flow (NOUT=184, NIN=8 even-strided z), 1 made (NOUT=32, NIN=16)
__global__ __launch_bounds__(256) void mega_kernel(
    const float* __restrict__ zg,       // [36864][16]
    const float* __restrict__ ctxout,   // [9216][384] : thw | gate1 | gate2 (gates pre-sigmoid'd)
    const float* __restrict__ inT,      // [NIN][128]
    const float* __restrict__ WT1,      // [2][128][128] k-major
    const float* __restrict__ WT2,      // [2][128][128]
    const float* __restrict__ bb1,      // [2][128]
    const float* __restrict__ bb2,      // [2][128]
    const float* __restrict__ WoutT,    // [128][NOUT] k-major
    const float* __restrict__ boutv,    // [NOUT]
    float* __restrict__ p)              // [36864][NOUT]
{
    constexpr int NOUT = MODE ? 32 : 184;
    constexpr int NIN  = MODE ? 16 : 8;
    __shared__ alignas(16) float tS[32][132];
    __shared__ alignas(16) float uS[32][132];
    const int tid  = threadIdx.x;
    const int rowg = tid >> 5;          // 0..7
    const int colg = tid & 31;          // 0..31
    const int m0   = blockIdx.x * 32;

    // ---- input layer: t = thw + z_in @ inT ----
    #pragma unroll
    for (int q = 0; q < 4; ++q) {
        int m = m0 + rowg * 4 + q;
        int hw = m >> 2;
        const float4* z4 = (const float4*)(zg + (size_t)m * 16);
        float4 za = z4[0], zb = z4[1], zc = z4[2], zd = z4[3];
        float zin[16] = {za.x, za.y, za.z, za.w, zb.x, zb.y, zb.z, zb.w,
                         zc.x, zc.y, zc.z, zc.w, zd.x, zd.y, zd.z, zd.w};
        const float* cbase = ctxout + (size_t)hw * 384 + colg * 4;
        #pragma unroll
        for (int r = 0; r < 4; ++r) {
            int n = colg * 4 + r;
            float acc = cbase[r];
            #pragma unroll
            for (int d = 0; d < NIN; ++d)
                acc = fmaf(zin[MODE ? d : 2 * d], inT[d * 128 + n], acc);
            tS[rowg * 4 + q][n] = acc;
        }
    }
    __syncthreads();

    // ---- residual blocks ----
    for (int blk = 0; blk < 2; ++blk) {
        float acc[4][4];
        tile_gemm128<true>(tS, WT1 + blk * 16384, rowg, colg, acc);
        #pragma unroll
        for (int q = 0; q < 4; ++q) {
            float4 uv;
            uv.x = acc[q][0] + bb1[blk * 128 + colg * 4 + 0];
            uv.y = acc[q][1] + bb1[blk * 128 + colg * 4 + 1];
            uv.z = acc[q][2] + bb1[blk * 128 + colg * 4 + 2];
            uv.w = acc[q][3] + bb1[blk * 128 + colg * 4 + 3];
            *(float4*)&uS[rowg * 4 + q][colg * 4] = uv;
        }
        __syncthreads();
        tile_gemm128<true>(uS, WT2 + blk * 16384, rowg, colg, acc);
        #pragma unroll
        for (int q = 0; q < 4; ++q) {
            int m = m0 + rowg * 4 + q;
            int hw = m >> 2;
            const float* gbase = ctxout + (size_t)hw * 384 + 128 + blk * 128 + colg * 4;
            #pragma unroll
            for (int r = 0; r < 4; ++r) {
                float v = (acc[q][r] + bb2[blk * 128 + colg * 4 + r]) * gbase[r];
                tS[rowg * 4 + q][colg * 4 + r] += v;
            }
        }
        __syncthreads();
    }

    // ---- output projection: p = t @ WoutT + bout ----
    for (int c0 = 0; c0 < NOUT; c0 += 128) {
        int nc = (NOUT - c0 < 128) ? (NOUT - c0) : 128;
        int n = c0 + colg * 4;
        if (colg * 4 < nc) {
            float acc[4][4];
            #pragma unroll
            for (int q = 0; q < 4; ++q)
                #pragma unroll
                for (int r = 0; r < 4; ++r)
                    acc[q][r] = 0.f;
            for (int k = 0; k < 128; k += 4) {
                float4 w0 = *(const float4*)(WoutT + (size_t)(k + 0) * NOUT + n);
                float4 w1 = *(const float4*)(WoutT + (size_t)(k + 1) * NOUT + n);
                float4 w2 = *(const float4*)(WoutT + (size_t)(k + 2) * NOUT + n);
                float4 w3 = *(const float4*)(WoutT + (size_t)(k + 3) * NOUT + n);
                #pragma unroll
                for (int q = 0; q < 4; ++q) {
                    float4 av = *(const float4*)&tS[rowg * 4 + q][k];
                    acc[q][0] = fmaf(av.w, w3.x, fmaf(av.z, w2.x, fmaf(av.y, w1.x, fmaf(av.x, w0.x, acc[q][0]))));
                    acc[q][1] = fmaf(av.w, w3.y, fmaf(av.z, w2.y, fmaf(av.y, w1.y, fmaf(av.x, w0.y, acc[q][1]))));
                    acc[q][2] = fmaf(av.w, w3.z, fmaf(av.z, w2.z, fmaf(av.y, w1.z, fmaf(av.x, w0.z, acc[q][2]))));
                    acc[q][3] = fmaf(av.w, w3.w, fmaf(av.z, w2.w, fmaf(av.y, w1.w, fmaf(av.x, w0.w, acc[q][3]))));
                }
            }
            #pragma unroll
            for (int q = 0; q < 4; ++q) {
                int m = m0 + rowg * 4 + q;
                float4 ov;
                ov.x = acc[q][0] + boutv[n + 0];
                ov.y = acc[q][1] + boutv[n + 1];
                ov.z = acc[q][2] + boutv[n + 2];
                ov.w = acc[q][3] + boutv[n + 3];
                *(float4*)(p + (size_t)m * NOUT + n) = ov;
            }
        }
    }
}

// ---------------- rational-quadratic spline ----------------
__device__ __forceinline__ void knots8(const float* __restrict__ u, float* c, float* w) {
    float mx = u[0];
    #pragma unroll
    for (int k = 1; k < 8; ++k) mx = fmaxf(mx, u[k]);
    float e[8]; float s = 0.f;
    #pragma unroll
    for (int k = 0; k < 8; ++k) { e[k] = expf(u[k] - mx); s += e[k]; }
    float inv = 1.f / s;
    c[0] = -3.f;
    float cum = 0.f;
    #pragma unroll
    for (int k = 0; k < 8; ++k) {
        float v = 0.001f + 0.992f * e[k] * inv;
        cum += v;
        c[k + 1] = cum * 6.f - 3.f;
    }
    c[8] = 3.f;
    #pragma unroll
    for (int k = 0; k < 8; ++k) w[k] = c[k + 1] - c[k];
}

__device__ __forceinline__ void rqs1(float x,
                                     const float* __restrict__ uw,
                                     const float* __restrict__ uh,
                                     const float* __restrict__ ud,
                                     float& y, float& ld) {
    float cw[9], wd[8], ch[9], hg[8], dd[9];
    knots8(uw, cw, wd);
    knots8(uh, ch, hg);
    dd[0] = 1.f; dd[8] = 1.f;
    #pragma unroll
    for (int k = 0; k < 7; ++k) dd[k + 1] = 0.001f + softplusf(ud[k]);
    bool inside = (x >= -3.f) && (x <= 3.f);
    float xc = fminf(fmaxf(x, -3.f), 3.f);
    float cwk = cw[0], wk = wd[0], chk = ch[0], hk = hg[0], d0 = dd[0], d1 = dd[1];
    #pragma unroll
    for (int k = 1; k < 8; ++k) {
        if (xc >= cw[k]) { cwk = cw[k]; wk = wd[k]; chk = ch[k]; hk = hg[k]; d0 = dd[k]; d1 = dd[k + 1]; }
    }
    float dl = hk / wk;
    float th = (xc - cwk) / wk;
    float t1 = th * (1.f - th);
    float den = dl + (d0 + d1 - 2.f * dl) * t1;
    float yy = chk + hk * (dl * th * th + d0 * t1) / den;
    float om = 1.f - th;
    float dnum = dl * dl * (d1 * th * th + 2.f * dl * t1 + d0 * om * om);
    float lld = logf(dnum) - 2.f * logf(den);
    y  = inside ? yy : x;
    ld = inside ? lld : 0.f;
}

__global__ __launch_bounds__(256) void spline_kernel(float* __restrict__ z,
                                                     const float* __restrict__ p,
                                                     const float* __restrict__ uw_id,
                                                     const float* __restrict__ uh_id,
                                                     const float* __restrict__ ud_id,
                                                     float* __restrict__ logq) {
    int e = blockIdx.x * 256 + threadIdx.x;
    if (e >= NROWS * 8) return;
    int dim = e & 7;
    int row = e >> 3;
    float zid = z[(size_t)row * 16 + 2 * dim];
    float ztr = z[(size_t)row * 16 + 2 * dim + 1];
    const float* pr = p + (size_t)row * 184 + dim * 23;
    const float inv_sqrt_h = 0.08838834764831845f;  // 1/sqrt(128)
    float uw[8], uh[8], ud[7];
    #pragma unroll
    for (int k = 0; k < 8; ++k) { uw[k] = pr[k] * inv_sqrt_h; uh[k] = pr[8 + k] * inv_sqrt_h; }
    #pragma unroll
    for (int k = 0; k < 7; ++k) ud[k] = pr[16 + k];
    float ytr, ldtr; rqs1(ztr, uw, uh, ud, ytr, ldtr);
    float yid, ldid; rqs1(zid, uw_id + dim * 8, uh_id + dim * 8, ud_id + dim * 7, yid, ldid);
    z[(size_t)row * 16 + 2 * dim]     = yid;
    z[(size_t)row * 16 + 2 * dim + 1] = ytr;
    float ld = ldtr + ldid;
    ld += __shfl_xor(ld, 1);
    ld += __shfl_xor(ld, 2);
    ld += __shfl_xor(ld, 4);
    if (dim == 0) logq[row] += ld;
}

// ---------------- MADE output: scale/shift z, accumulate log|scale| ----------------
__global__ __launch_bounds__(256) void made_out_kernel(const float* __restrict__ ar,
                                                       float* __restrict__ z,
                                                       float* __restrict__ logq) {
    int row = blockIdx.x * 256 + threadIdx.x;
    if (row >= NROWS) return;
    const float* a = ar + (size_t)row * 32;
    float* zr = z + (size_t)row * 16;
    float lacc = 0.f;
    #pragma unroll
    for (int d = 0; d < 16; ++d) {
        float s = softplusf(a[2 * d]) + 0.001f;
        zr[d] = s * zr[d] + a[2 * d + 1];
        lacc += logf(s);
    }
    logq[row] += lacc;
}

// ---------------- Gaussian head + output transpose ----------------
__global__ __launch_bounds__(256) void final_kernel(const float* __restrict__ z,
                                                    const float* __restrict__ ehw,
                                                    const float* __restrict__ logq,
                                                    float* __restrict__ out) {
    int row = blockIdx.x * 256 + threadIdx.x;
    if (row >= NROWS) return;
    int hw = row >> 2, b = row & 3;
    const float* e = ehw + (size_t)hw * 32;
    const float* zr = z + (size_t)row * 16;
    float lq = logq[row] - 14.703016531274762f;  // -0.5*16*log(2*pi)
    #pragma unroll
    for (int d = 0; d < 16; ++d) {
        float ls = e[16 + d];
        float diff = (zr[d] - e[d]) * expf(-ls);
        lq -= ls + 0.5f * diff * diff;
    }
    out[(size_t)b * NHW + hw] = lq;
}

extern "C" void kernel_launch(void* const* d_in, const int* in_sizes, int n_in,
                              void* d_out, int out_size, void* d_ws, size_t ws_size,
                              hipStream_t stream) {
    (void)in_sizes; (void)n_in; (void)out_size; (void)ws_size;
    const float* x         = (const float*)d_in[0];
    const float* made_W0   = (const float*)d_in[1];
    const float* made_b0   = (const float*)d_in[2];
    const float* made_ctxW = (const float*)d_in[3];
    const float* made_ctxb = (const float*)d_in[4];
    const float* made_bW1  = (const float*)d_in[5];
    const float* made_bb1  = (const float*)d_in[6];
    const float* made_bW2  = (const float*)d_in[7];
    const float* made_bb2  = (const float*)d_in[8];
    const float* made_bCW  = (const float*)d_in[9];
    const float* made_bCb  = (const float*)d_in[10];
    const float* made_Wout = (const float*)d_in[11];
    const float* made_bout = (const float*)d_in[12];
    const float* sp_Win    = (const float*)d_in[13];
    const float* sp_bin    = (const float*)d_in[14];
    const float* sp_bW1    = (const float*)d_in[15];
    const float* sp_bb1    = (const float*)d_in[16];
    const float* sp_bW2    = (const float*)d_in[17];
    const float* sp_bb2    = (const float*)d_in[18];
    const float* sp_bCW    = (const float*)d_in[19];
    const float* sp_bCb    = (const float*)d_in[20];
    const float* sp_Wout   = (const float*)d_in[21];
    const float* sp_bout   = (const float*)d_in[22];
    const float* sp_uw     = (const float*)d_in[23];
    const float* sp_uh     = (const float*)d_in[24];
    const float* sp_ud     = (const float*)d_in[25];
    const float* lu_lower  = (const float*)d_in[26];
    const float* lu_upper  = (const float*)d_in[27];
    const float* lu_udiag  = (const float*)d_in[28];
    const float* lu_bias   = (const float*)d_in[29];
    const int*   lu_perm   = (const int*)d_in[30];
    const float* enc_W1    = (const float*)d_in[31];
    const float* enc_b1    = (const float*)d_in[32];
    const float* enc_W2    = (const float*)d_in[33];
    const float* enc_b2    = (const float*)d_in[34];
    float* out = (float*)d_out;

    float* ws      = (float*)d_ws;
    float* ctx     = ws;                               // 9216*128
    float* ctxout  = ctx     + (size_t)NHW * 128;      // 9216*384
    float* z       = ctxout  + (size_t)NHW * 384;      // 36864*16
    float* logq    = z       + (size_t)NROWS * 16;     // 36864
    float* p       = logq    + NROWS;                  // 36864*184
    float* thw_enc = p       + (size_t)NROWS * 184;    // 9216*128
    float* ehw     = thw_enc + (size_t)NHW * 128;      // 9216*32
    float* fWT1    = ehw     + (size_t)NHW * 32;       // 8*16384
    float* fWT2    = fWT1    + 8 * 16384;              // 8*16384
    float* mWT1    = fWT2    + 8 * 16384;              // 2*16384
    float* mWT2    = mWT1    + 2 * 16384;              // 2*16384
    float* fWoutT  = mWT2    + 2 * 16384;              // 4*23552
    float* mWoutT  = fWoutT  + 4 * 23552;              // 4096
    float* fwinzT  = mWoutT  + 4096;                   // 4*1024
    float* mW0T    = fwinzT  + 4 * 1024;               // 2048
    float* fpw     = mW0T    + 2048;                   // 4*49152
    float* mpw     = fpw     + 4 * 49152;              // 49152
    float* fpb     = mpw     + 49152;                  // 4*384
    float* mpb     = fpb     + 4 * 384;                // 384

    dim3 B(256);
    pack_kernel<<<dim3(768, 12), B, 0, stream>>>(
        sp_bW1, sp_bW2, made_bW1, made_bW2, sp_Wout, made_Wout, sp_Win, made_W0,
        sp_bCW, made_ctxW, made_bCW, sp_bin, sp_bCb, made_ctxb, made_b0, made_bCb,
        fWT1, fWT2, mWT1, mWT2, fWoutT, mWoutT, fwinzT, mW0T, fpw, mpw, fpb, mpb);
    ctx_kernel<<<4608, B, 0, stream>>>(ctx);
    snorm_kernel<<<2304, B, 0, stream>>>(x, z);
    initlogq_kernel<<<144, B, 0, stream>>>(lu_udiag, logq);

    for (int i = 3; i >= 0; --i) {
        lu_kernel<<<144, B, 0, stream>>>(z, lu_lower + i * 256, lu_upper + i * 256,
                                         lu_udiag + i * 16, lu_bias + i * 16, lu_perm + i * 16);
        gemm_k<4><<<dim3(144, 6), B, 0, stream>>>(ctx, 128, fpw + (size_t)i * 49152, 128,
                                                  fpb + i * 384, ctxout, 384, NHW, 384, 128);
        mega_kernel<0><<<1152, B, 0, stream>>>(z, ctxout, fwinzT + i * 1024,
                                               fWT1 + i * 32768, fWT2 + i * 32768,
                                               sp_bb1 + i * 256, sp_bb2 + i * 256,
                                               fWoutT + i * 23552, sp_bout + i * 184, p);
        spline_kernel<<<1152, B, 0, stream>>>(z, p, sp_uw + i * 64, sp_uh + i * 64, sp_ud + i * 56, logq);
    }

    // ---- MADE ----
    gemm_k<4><<<dim3(144, 6), B, 0, stream>>>(ctx, 128, mpw, 128, mpb, ctxout, 384, NHW, 384, 128);
    mega_kernel<1><<<1152, B, 0, stream>>>(z, ctxout, mW0T, mWT1, mWT2,
                                           made_bb1, made_bb2, mWoutT, made_bout, p);
    made_out_kernel<<<144, B, 0, stream>>>(p, z, logq);

    // ---- encoder (per-hw) ----
    gemm_k<2><<<dim3(144, 2), B, 0, stream>>>(ctx, 128, enc_W1, 128, enc_b1, thw_enc, 128, NHW, 128, 128);
    gemm_k<0><<<dim3(144, 1), B, 0, stream>>>(thw_enc, 128, enc_W2, 128, enc_b2, ehw, 32, NHW, 32, 128);
    final_kernel<<<144, B, 0, stream>>>(z, ehw, logq, out);
}

// Round 4
// 625.982 us; speedup vs baseline: 2.0028x; 1.5582x over previous
//
#include <hip/hip_runtime.h>
#include <math.h>

#define NHW   9216     // 96*96
#define NROWS 36864    // NHW*4

typedef _Float16 f16;
typedef _Float16 f16x8 __attribute__((ext_vector_type(8)));
typedef float    f32x4 __attribute__((ext_vector_type(4)));

__device__ __forceinline__ float softplusf(float x) {
    return fmaxf(x, 0.f) + log1pf(expf(-fabsf(x)));
}

// ---------------- positional encoding ctx[hw][128] ----------------
__global__ __launch_bounds__(256) void ctx_kernel(float* __restrict__ ctx) {
    int e = blockIdx.x * 256 + threadIdx.x;
    if (e >= NHW * 128) return;
    int c  = e & 127;
    int hw = e >> 7;
    int i = hw / 96, j = hw % 96;
    int pos = (c < 64) ? i : j;
    int cc = c & 63;
    int k = cc >> 1;
    float invf = powf(10000.f, -(float)k / 32.f);
    float v = (float)pos * invf;
    ctx[e] = (cc & 1) ? cosf(v) : sinf(v);
}

// ---------------- spatial_norm -> z[row][16], row = (i*96+j)*4+b ----------------
__global__ __launch_bounds__(256) void snorm_kernel(const float* __restrict__ x,
                                                    float* __restrict__ z) {
    int e = blockIdx.x * 256 + threadIdx.x;
    if (e >= NROWS * 16) return;
    int j = e % 96;
    int i = (e / 96) % 96;
    int s = (e / 9216) % 16;
    int b = e / (9216 * 16);
    float sum = 0.f;
    const float* xb = x + (size_t)((b * 16 + s) * 3) * 192 * 192;
    #pragma unroll
    for (int c = 0; c < 3; ++c) {
        const float* xc = xb + (size_t)c * 192 * 192;
        #pragma unroll
        for (int dh = -1; dh <= 1; ++dh) {
            int hh = 2 * i + dh;
            if (hh < 0 || hh >= 192) continue;
            const float* xr = xc + hh * 192;
            #pragma unroll
            for (int dw = -1; dw <= 1; ++dw) {
                int ww = 2 * j + dw;
                if (ww < 0 || ww >= 192) continue;
                float v = xr[ww];
                sum += v * v;
            }
        }
    }
    int row = (i * 96 + j) * 4 + b;
    z[(size_t)row * 16 + s] = sqrtf(sum);
}

// ---------------- init logq with sum of LU log-dets (constant) ----------------
__global__ __launch_bounds__(256) void initlogq_kernel(const float* __restrict__ lu_udiag,
                                                       float* __restrict__ logq) {
    int row = blockIdx.x * 256 + threadIdx.x;
    if (row >= NROWS) return;
    float c0 = 0.f;
    for (int k = 0; k < 64; ++k)
        c0 += logf(softplusf(lu_udiag[k]) + 0.001f);
    logq[row] = c0;
}

// ---------------- LU transform: z = L(U z_perm) + bias (in place per row) ----------------
__global__ __launch_bounds__(256) void lu_kernel(float* __restrict__ z,
                                                 const float* __restrict__ lower,
                                                 const float* __restrict__ upper,
                                                 const float* __restrict__ udiag_raw,
                                                 const float* __restrict__ bias,
                                                 const int* __restrict__ perm) {
    int row = blockIdx.x * 256 + threadIdx.x;
    if (row >= NROWS) return;
    float* zr = z + (size_t)row * 16;
    float zp[16], y[16];
    #pragma unroll
    for (int d = 0; d < 16; ++d) zp[d] = zr[perm[d]];
    #pragma unroll
    for (int r = 0; r < 16; ++r) {
        float acc = (softplusf(udiag_raw[r]) + 0.001f) * zp[r];
        #pragma unroll
        for (int c = 0; c < 16; ++c)
            if (c > r) acc += upper[r * 16 + c] * zp[c];
        y[r] = acc;
    }
    #pragma unroll
    for (int r = 0; r < 16; ++r) {
        float acc = y[r] + bias[r];
        #pragma unroll
        for (int c = 0; c < 16; ++c)
            if (c < r) acc += lower[r * 16 + c] * y[c];
        zr[r] = acc;
    }
}

// ---------------- one-time weight pack kernel ----------------
// MFMA B-fragment order for a [N][K] weight (K=128): frag element
//   f = ((nt*4+ks)*64 + l)*8 + j  ->  n = nt*16+(l&15), k = ks*32+((l>>4)&3)*8+j
// cat 0: fW1f (f16) 8 mats x16384 = T-frag(sp_bW1)
// cat 1: fW2f (f16)
// cat 2: mW1f (f16) 2 mats, MASK_HID
// cat 3: mW2f (f16) 2 mats, MASK_HID
// cat 4: fWoutf (f16) 4 x 12nt x4ks x64 x8 (184 cols padded to 192)
// cat 5: mWoutf (f16) 2nt, MASK_OUT
// cat 6: fwinzT[4][8][128] f32; cat 7: mW0T[16][128] f32 (MASK_IN)
// cat 8: fpw[4][384][128]; cat 9: mpw[384][128]; cat 10: fpb; cat 11: mpb
__global__ __launch_bounds__(256) void pack_kernel(
    const float* __restrict__ sp_bW1, const float* __restrict__ sp_bW2,
    const float* __restrict__ made_bW1, const float* __restrict__ made_bW2,
    const float* __restrict__ sp_Wout, const float* __restrict__ made_Wout,
    const float* __restrict__ sp_Win, const float* __restrict__ made_W0,
    const float* __restrict__ sp_bCW, const float* __restrict__ made_ctxW,
    const float* __restrict__ made_bCW,
    const float* __restrict__ sp_bin, const float* __restrict__ sp_bCb,
    const float* __restrict__ made_ctxb, const float* __restrict__ made_b0,
    const float* __restrict__ made_bCb,
    f16* __restrict__ fW1f, f16* __restrict__ fW2f,
    f16* __restrict__ mW1f, f16* __restrict__ mW2f,
    f16* __restrict__ fWoutf, f16* __restrict__ mWoutf,
    float* __restrict__ fwinzT, float* __restrict__ mW0T,
    float* __restrict__ fpw, float* __restrict__ mpw,
    float* __restrict__ fpb, float* __restrict__ mpb)
{
    int cat = blockIdx.y;
    int e = blockIdx.x * 256 + threadIdx.x;
    switch (cat) {
    case 0: if (e < 8 * 16384) {
        int mtx = e >> 14, f = e & 16383;
        int nt = f >> 11, ks = (f >> 9) & 3, l = (f >> 3) & 63, j = f & 7;
        int n = nt * 16 + (l & 15), k = ks * 32 + ((l >> 4) & 3) * 8 + j;
        fW1f[e] = (f16)sp_bW1[mtx * 16384 + n * 128 + k];
    } break;
    case 1: if (e < 8 * 16384) {
        int mtx = e >> 14, f = e & 16383;
        int nt = f >> 11, ks = (f >> 9) & 3, l = (f >> 3) & 63, j = f & 7;
        int n = nt * 16 + (l & 15), k = ks * 32 + ((l >> 4) & 3) * 8 + j;
        fW2f[e] = (f16)sp_bW2[mtx * 16384 + n * 128 + k];
    } break;
    case 2: if (e < 2 * 16384) {
        int mtx = e >> 14, f = e & 16383;
        int nt = f >> 11, ks = (f >> 9) & 3, l = (f >> 3) & 63, j = f & 7;
        int n = nt * 16 + (l & 15), k = ks * 32 + ((l >> 4) & 3) * 8 + j;
        mW1f[e] = ((n % 15) >= (k % 15)) ? (f16)made_bW1[mtx * 16384 + n * 128 + k] : (f16)0.f;
    } break;
    case 3: if (e < 2 * 16384) {
        int mtx = e >> 14, f = e & 16383;
        int nt = f >> 11, ks = (f >> 9) & 3, l = (f >> 3) & 63, j = f & 7;
        int n = nt * 16 + (l & 15), k = ks * 32 + ((l >> 4) & 3) * 8 + j;
        mW2f[e] = ((n % 15) >= (k % 15)) ? (f16)made_bW2[mtx * 16384 + n * 128 + k] : (f16)0.f;
    } break;
    case 4: if (e < 4 * 24576) {
        int s = e / 24576, f = e % 24576;
        int nt = f >> 11, ks = (f >> 9) & 3, l = (f >> 3) & 63, j = f & 7;
        int n = nt * 16 + (l & 15), k = ks * 32 + ((l >> 4) & 3) * 8 + j;
        fWoutf[e] = (n < 184) ? (f16)sp_Wout[s * 23552 + n * 128 + k] : (f16)0.f;
    } break;
    case 5: if (e < 4096) {
        int f = e;
        int nt = f >> 11, ks = (f >> 9) & 3, l = (f >> 3) & 63, j = f & 7;
        int n = nt * 16 + (l & 15), k = ks * 32 + ((l >> 4) & 3) * 8 + j;
        mWoutf[e] = (((n & 15) > (k % 15)) && n < 32) ? (f16)made_Wout[n * 128 + k] : (f16)0.f;
    } break;
    case 6: if (e < 4 * 1024) {
        int s = e >> 10, r = e & 1023, d = r >> 7, h = r & 127;
        fwinzT[e] = sp_Win[s * 17408 + h * 136 + d];
    } break;
    case 7: if (e < 2048) {
        int d = e >> 7, h = e & 127;
        mW0T[e] = ((h % 15) >= d) ? made_W0[h * 16 + d] : 0.f;
    } break;
    case 8: if (e < 4 * 49152) {
        int s = e / 49152, r = e % 49152, n = r >> 7, k = r & 127;
        float v;
        if (n < 128)      v = sp_Win[s * 17408 + n * 136 + 8 + k];
        else if (n < 256) v = sp_bCW[(size_t)(s * 2 + 0) * 16384 + (n - 128) * 128 + k];
        else              v = sp_bCW[(size_t)(s * 2 + 1) * 16384 + (n - 256) * 128 + k];
        fpw[e] = v;
    } break;
    case 9: if (e < 49152) {
        int n = e >> 7, k = e & 127;
        float v;
        if (n < 128)      v = made_ctxW[n * 128 + k];
        else if (n < 256) v = made_bCW[(n - 128) * 128 + k];
        else              v = made_bCW[16384 + (n - 256) * 128 + k];
        mpw[e] = v;
    } break;
    case 10: if (e < 4 * 384) {
        int s = e / 384, n = e % 384;
        float v;
        if (n < 128)      v = sp_bin[s * 128 + n];
        else if (n < 256) v = sp_bCb[(s * 2 + 0) * 128 + (n - 128)];
        else              v = sp_bCb[(s * 2 + 1) * 128 + (n - 256)];
        fpb[e] = v;
    } break;
    case 11: if (e < 384) {
        float v;
        if (e < 128)      v = made_ctxb[e] + made_b0[e];
        else if (e < 256) v = made_bCb[e - 128];
        else              v = made_bCb[128 + (e - 256)];
        mpb[e] = v;
    } break;
    }
}

// ---------------- tiled f32 GEMM (ctx / encoder): C = post(A @ W^T + bias) ----------------
// POST: 0 store, 2 silu, 4 mixed (n<128 store, else sigmoid)
template<int POST>
__global__ __launch_bounds__(256) void gemm_k(
    const float* __restrict__ A, int lda,
    const float* __restrict__ W, int ldw,
    const float* __restrict__ bias,
    float* __restrict__ C, int ldc,
    int M, int N, int K)
{
    __shared__ alignas(16) float As[16][68];
    __shared__ alignas(16) float Ws[16][68];
    const int tid = threadIdx.x;
    const int m0 = blockIdx.x * 64;
    const int n0 = blockIdx.y * 64;
    const int tm = (tid >> 4) << 2;
    const int tn = (tid & 15) << 2;
    const int srow = tid >> 2;
    const int skq  = (tid & 3) << 2;

    float acc[4][4] = {{0.f,0.f,0.f,0.f},{0.f,0.f,0.f,0.f},{0.f,0.f,0.f,0.f},{0.f,0.f,0.f,0.f}};

    for (int k0 = 0; k0 < K; k0 += 16) {
        float4 av = *(const float4*)(A + (size_t)(m0 + srow) * lda + k0 + skq);
        As[skq + 0][srow] = av.x; As[skq + 1][srow] = av.y;
        As[skq + 2][srow] = av.z; As[skq + 3][srow] = av.w;
        int wn = n0 + srow;
        float4 wv = make_float4(0.f, 0.f, 0.f, 0.f);
        if (wn < N) wv = *(const float4*)(W + (size_t)wn * ldw + k0 + skq);
        Ws[skq + 0][srow] = wv.x; Ws[skq + 1][srow] = wv.y;
        Ws[skq + 2][srow] = wv.z; Ws[skq + 3][srow] = wv.w;
        __syncthreads();
        #pragma unroll
        for (int kk = 0; kk < 16; ++kk) {
            float4 a4 = *(const float4*)&As[kk][tm];
            float4 w4 = *(const float4*)&Ws[kk][tn];
            float aa[4] = {a4.x, a4.y, a4.z, a4.w};
            float wwv[4] = {w4.x, w4.y, w4.z, w4.w};
            #pragma unroll
            for (int q = 0; q < 4; ++q)
                #pragma unroll
                for (int r = 0; r < 4; ++r)
                    acc[q][r] = fmaf(aa[q], wwv[r], acc[q][r]);
        }
        __syncthreads();
    }
    #pragma unroll
    for (int q = 0; q < 4; ++q) {
        int m = m0 + tm + q;
        #pragma unroll
        for (int r = 0; r < 4; ++r) {
            int n = n0 + tn + r;
            if (n < N) {
                float val = acc[q][r] + bias[n];
                float* cp = C + (size_t)m * ldc + n;
                if (POST == 0)      *cp = val;
                else if (POST == 2) *cp = val / (1.f + expf(-val));
                else                *cp = (n < 128) ? val : 1.f / (1.f + expf(-val));
            }
        }
    }
}

// ---------------- MFMA mega kernel: input layer + 2 residual blocks + Wout ----------------
// block = 256 threads = 4 waves; each wave owns a private 16-row stripe.
// t/u live in LDS as f16 [16][136] per wave. Weights consumed as pre-packed B-fragments.
// MFMA D layout (m89-verified): col = lane&15, row = (lane>>4)*4 + reg.
// A from LDS / B from frags use the identical (lane,j)->k map, so the contraction is exact.
template<int MODE>   // 0 flow (NOUT=184 pad 192, NIN=8 even z), 1 made (NOUT=32, NIN=16)
__global__ __launch_bounds__(256) void mega_mfma(
    const float* __restrict__ zg,       // [36864][16]
    const float* __restrict__ ctxout,   // [9216][384] thw | gate1 | gate2 (pre-sigmoided)
    const float* __restrict__ inT,      // [NIN][128] f32
    const f16*  __restrict__ W1f,       // [2][16384] fragment order
    const f16*  __restrict__ W2f,       // [2][16384]
    const float* __restrict__ bb1,      // [2][128]
    const float* __restrict__ bb2,      // [2][128]
    const f16*  __restrict__ Woutf,     // [NTO*2048]
    const float* __restrict__ boutv,    // [NOUT]
    float* __restrict__ p)              // [36864][NOUT]
{
    constexpr int NOUT = MODE ? 32 : 184;
    constexpr int NTO  = MODE ? 2 : 12;
    constexpr int NIN  = MODE ? 16 : 8;
    __shared__ alignas(16) f16 tS[4][16][136];
    __shared__ alignas(16) f16 uS[4][16][136];
    const int tid = threadIdx.x;
    const int w   = tid >> 6;          // wave 0..3
    const int l   = tid & 63;
    const int m0  = blockIdx.x * 64 + w * 16;
    const int lr  = l & 15;
    const int lq  = l >> 4;

    // ---- input layer: t = thw + z_in @ inT ----
    {
        const int r  = l >> 2;
        const int c0 = (l & 3) * 32;
        const int gm = m0 + r;
        const int hw = gm >> 2;
        const float* zr = zg + (size_t)gm * 16;
        float zin[NIN];
        #pragma unroll
        for (int d = 0; d < NIN; ++d) zin[d] = zr[MODE ? d : 2 * d];
        const float* cb = ctxout + (size_t)hw * 384 + c0;
        #pragma unroll
        for (int c = 0; c < 32; ++c) {
            float acc = cb[c];
            #pragma unroll
            for (int d = 0; d < NIN; ++d)
                acc = fmaf(zin[d], inT[d * 128 + c0 + c], acc);
            tS[w][r][c0 + c] = (f16)acc;
        }
    }
    __syncthreads();

    const f32x4 vzero = {0.f, 0.f, 0.f, 0.f};

    // ---- residual blocks ----
    #pragma unroll
    for (int blk = 0; blk < 2; ++blk) {
        // u_pre = relu(t) @ W1 + b1
        f32x4 acc[8];
        #pragma unroll
        for (int nt = 0; nt < 8; ++nt) acc[nt] = vzero;
        #pragma unroll
        for (int ks = 0; ks < 4; ++ks) {
            f16x8 a = *(const f16x8*)&tS[w][lr][ks * 32 + lq * 8];
            #pragma unroll
            for (int j = 0; j < 8; ++j) a[j] = a[j] > (f16)0.f ? a[j] : (f16)0.f;
            const f16* wb = W1f + (size_t)blk * 16384 + (ks * 64 + l) * 8;
            #pragma unroll
            for (int nt = 0; nt < 8; ++nt) {
                f16x8 b = *(const f16x8*)(wb + nt * 2048);
                acc[nt] = __builtin_amdgcn_mfma_f32_16x16x32_f16(a, b, acc[nt], 0, 0, 0);
            }
        }
        #pragma unroll
        for (int nt = 0; nt < 8; ++nt) {
            float bias = bb1[blk * 128 + nt * 16 + lr];
            #pragma unroll
            for (int r = 0; r < 4; ++r)
                uS[w][lq * 4 + r][nt * 16 + lr] = (f16)(acc[nt][r] + bias);
        }
        __syncthreads();

        // t += (relu(u_pre) @ W2 + b2) * gate
        #pragma unroll
        for (int nt = 0; nt < 8; ++nt) acc[nt] = vzero;
        #pragma unroll
        for (int ks = 0; ks < 4; ++ks) {
            f16x8 a = *(const f16x8*)&uS[w][lr][ks * 32 + lq * 8];
            #pragma unroll
            for (int j = 0; j < 8; ++j) a[j] = a[j] > (f16)0.f ? a[j] : (f16)0.f;
            const f16* wb = W2f + (size_t)blk * 16384 + (ks * 64 + l) * 8;
            #pragma unroll
            for (int nt = 0; nt < 8; ++nt) {
                f16x8 b = *(const f16x8*)(wb + nt * 2048);
                acc[nt] = __builtin_amdgcn_mfma_f32_16x16x32_f16(a, b, acc[nt], 0, 0, 0);
            }
        }
        {
            const int hw = (m0 + lq * 4) >> 2;   // 4 consecutive rows share one hw
            const float* gb = ctxout + (size_t)hw * 384 + 128 + blk * 128;
            #pragma unroll
            for (int nt = 0; nt < 8; ++nt) {
                float bias = bb2[blk * 128 + nt * 16 + lr];
                float g = gb[nt * 16 + lr];
                #pragma unroll
                for (int r = 0; r < 4; ++r) {
                    float tv = (float)tS[w][lq * 4 + r][nt * 16 + lr];
                    tS[w][lq * 4 + r][nt * 16 + lr] = (f16)(tv + (acc[nt][r] + bias) * g);
                }
            }
        }
        __syncthreads();
    }

    // ---- output projection: p = t @ Wout + bout (no relu) ----
    f32x4 po[NTO];
    #pragma unroll
    for (int nt = 0; nt < NTO; ++nt) po[nt] = vzero;
    #pragma unroll
    for (int ks = 0; ks < 4; ++ks) {
        f16x8 a = *(const f16x8*)&tS[w][lr][ks * 32 + lq * 8];
        const f16* wb = Woutf + (ks * 64 + l) * 8;
        #pragma unroll
        for (int nt = 0; nt < NTO; ++nt) {
            f16x8 b = *(const f16x8*)(wb + nt * 2048);
            po[nt] = __builtin_amdgcn_mfma_f32_16x16x32_f16(a, b, po[nt], 0, 0, 0);
        }
    }
    #pragma unroll
    for (int nt = 0; nt < NTO; ++nt) {
        int n = nt * 16 + lr;
        if (n < NOUT) {
            float bias = boutv[n];
            #pragma unroll
            for (int r = 0; r < 4; ++r) {
                int gm = m0 + lq * 4 + r;
                p[(size_t)gm * NOUT + n] = po[nt][r] + bias;
            }
        }
    }
}

// ---------------- rational-quadratic spline ----------------
__device__ __forceinline__ void knots8(const float* __restrict__ u, float* c, float* w) {
    float mx = u[0];
    #pragma unroll
    for (int k = 1; k < 8; ++k) mx = fmaxf(mx, u[k]);
    float e[8]; float s = 0.f;
    #pragma unroll
    for (int k = 0; k < 8; ++k) { e[k] = expf(u[k] - mx); s += e[k]; }
    float inv = 1.f / s;
    c[0] = -3.f;
    float cum = 0.f;
    #pragma unroll
    for (int k = 0; k < 8; ++k) {
        float v = 0.001f + 0.992f * e[k] * inv;
        cum += v;
        c[k + 1] = cum * 6.f - 3.f;
    }
    c[8] = 3.f;
    #pragma unroll
    for (int k = 0; k < 8; ++k) w[k] = c[k + 1] - c[k];
}

__device__ __forceinline__ void rqs1(float x,
                                     const float* __restrict__ uw,
                                     const float* __restrict__ uh,
                                     const float* __restrict__ ud,
                                     float& y, float& ld) {
    float cw[9], wd[8], ch[9], hg[8], dd[9];
    knots8(uw, cw, wd);
    knots8(uh, ch, hg);
    dd[0] = 1.f; dd[8] = 1.f;
    #pragma unroll
    for (int k = 0; k < 7; ++k) dd[k + 1] = 0.001f + softplusf(ud[k]);
    bool inside = (x >= -3.f) && (x <= 3.f);
    float xc = fminf(fmaxf(x, -3.f), 3.f);
    float cwk = cw[0], wk = wd[0], chk = ch[0], hk = hg[0], d0 = dd[0], d1 = dd[1];
    #pragma unroll
    for (int k = 1; k < 8; ++k) {
        if (xc >= cw[k]) { cwk = cw[k]; wk = wd[k]; chk = ch[k]; hk = hg[k]; d0 = dd[k]; d1 = dd[k + 1]; }
    }
    float dl = hk / wk;
    float th = (xc - cwk) / wk;
    float t1 = th * (1.f - th);
    float den = dl + (d0 + d1 - 2.f * dl) * t1;
    float yy = chk + hk * (dl * th * th + d0 * t1) / den;
    float om = 1.f - th;
    float dnum = dl * dl * (d1 * th * th + 2.f * dl * t1 + d0 * om * om);
    float lld = logf(dnum) - 2.f * logf(den);
    y  = inside ? yy : x;
    ld = inside ? lld : 0.f;
}

__global__ __launch_bounds__(256) void spline_kernel(float* __restrict__ z,
                                                     const float* __restrict__ p,
                                                     const float* __restrict__ uw_id,
                                                     const float* __restrict__ uh_id,
                                                     const float* __restrict__ ud_id,
                                                     float* __restrict__ logq) {
    int e = blockIdx.x * 256 + threadIdx.x;
    if (e >= NROWS * 8) return;
    int dim = e & 7;
    int row = e >> 3;
    float zid = z[(size_t)row * 16 + 2 * dim];
    float ztr = z[(size_t)row * 16 + 2 * dim + 1];
    const float* pr = p + (size_t)row * 184 + dim * 23;
    const float inv_sqrt_h = 0.08838834764831845f;  // 1/sqrt(128)
    float uw[8], uh[8], ud[7];
    #pragma unroll
    for (int k = 0; k < 8; ++k) { uw[k] = pr[k] * inv_sqrt_h; uh[k] = pr[8 + k] * inv_sqrt_h; }
    #pragma unroll
    for (int k = 0; k < 7; ++k) ud[k] = pr[16 + k];
    float ytr, ldtr; rqs1(ztr, uw, uh, ud, ytr, ldtr);
    float yid, ldid; rqs1(zid, uw_id + dim * 8, uh_id + dim * 8, ud_id + dim * 7, yid, ldid);
    z[(size_t)row * 16 + 2 * dim]     = yid;
    z[(size_t)row * 16 + 2 * dim + 1] = ytr;
    float ld = ldtr + ldid;
    ld += __shfl_xor(ld, 1);
    ld += __shfl_xor(ld, 2);
    ld += __shfl_xor(ld, 4);
    if (dim == 0) logq[row] += ld;
}

// ---------------- MADE output: scale/shift z, accumulate log|scale| ----------------
__global__ __launch_bounds__(256) void made_out_kernel(const float* __restrict__ ar,
                                                       float* __restrict__ z,
                                                       float* __restrict__ logq) {
    int row = blockIdx.x * 256 + threadIdx.x;
    if (row >= NROWS) return;
    const float* a = ar + (size_t)row * 32;
    float* zr = z + (size_t)row * 16;
    float lacc = 0.f;
    #pragma unroll
    for (int d = 0; d < 16; ++d) {
        float s = softplusf(a[2 * d]) + 0.001f;
        zr[d] = s * zr[d] + a[2 * d + 1];
        lacc += logf(s);
    }
    logq[row] += lacc;
}

// ---------------- Gaussian head + output transpose ----------------
__global__ __launch_bounds__(256) void final_kernel(const float* __restrict__ z,
                                                    const float* __restrict__ ehw,
                                                    const float* __restrict__ logq,
                                                    float* __restrict__ out) {
    int row = blockIdx.x * 256 + threadIdx.x;
    if (row >= NROWS) return;
    int hw = row >> 2, b = row & 3;
    const float* e = ehw + (size_t)hw * 32;
    const float* zr = z + (size_t)row * 16;
    float lq = logq[row] - 14.703016531274762f;  // -0.5*16*log(2*pi)
    #pragma unroll
    for (int d = 0; d < 16; ++d) {
        float ls = e[16 + d];
        float diff = (zr[d] - e[d]) * expf(-ls);
        lq -= ls + 0.5f * diff * diff;
    }
    out[(size_t)b * NHW + hw] = lq;
}

extern "C" void kernel_launch(void* const* d_in, const int* in_sizes, int n_in,
                              void* d_out, int out_size, void* d_ws, size_t ws_size,
                              hipStream_t stream) {
    (void)in_sizes; (void)n_in; (void)out_size; (void)ws_size;
    const float* x         = (const float*)d_in[0];
    const float* made_W0   = (const float*)d_in[1];
    const float* made_b0   = (const float*)d_in[2];
    const float* made_ctxW = (const float*)d_in[3];
    const float* made_ctxb = (const float*)d_in[4];
    const float* made_bW1  = (const float*)d_in[5];
    const float* made_bb1  = (const float*)d_in[6];
    const float* made_bW2  = (const float*)d_in[7];
    const float* made_bb2  = (const float*)d_in[8];
    const float* made_bCW  = (const float*)d_in[9];
    const float* made_bCb  = (const float*)d_in[10];
    const float* made_Wout = (const float*)d_in[11];
    const float* made_bout = (const float*)d_in[12];
    const float* sp_Win    = (const float*)d_in[13];
    const float* sp_bin    = (const float*)d_in[14];
    const float* sp_bW1    = (const float*)d_in[15];
    const float* sp_bb1    = (const float*)d_in[16];
    const float* sp_bW2    = (const float*)d_in[17];
    const float* sp_bb2    = (const float*)d_in[18];
    const float* sp_bCW    = (const float*)d_in[19];
    const float* sp_bCb    = (const float*)d_in[20];
    const float* sp_Wout   = (const float*)d_in[21];
    const float* sp_bout   = (const float*)d_in[22];
    const float* sp_uw     = (const float*)d_in[23];
    const float* sp_uh     = (const float*)d_in[24];
    const float* sp_ud     = (const float*)d_in[25];
    const float* lu_lower  = (const float*)d_in[26];
    const float* lu_upper  = (const float*)d_in[27];
    const float* lu_udiag  = (const float*)d_in[28];
    const float* lu_bias   = (const float*)d_in[29];
    const int*   lu_perm   = (const int*)d_in[30];
    const float* enc_W1    = (const float*)d_in[31];
    const float* enc_b1    = (const float*)d_in[32];
    const float* enc_W2    = (const float*)d_in[33];
    const float* enc_b2    = (const float*)d_in[34];
    float* out = (float*)d_out;

    float* ws      = (float*)d_ws;
    float* ctx     = ws;                               // 9216*128
    float* ctxout  = ctx     + (size_t)NHW * 128;      // 9216*384
    float* z       = ctxout  + (size_t)NHW * 384;      // 36864*16
    float* logq    = z       + (size_t)NROWS * 16;     // 36864
    float* p       = logq    + NROWS;                  // 36864*184
    float* thw_enc = p       + (size_t)NROWS * 184;    // 9216*128
    float* ehw     = thw_enc + (size_t)NHW * 128;      // 9216*32
    float* fwinzT  = ehw     + (size_t)NHW * 32;       // 4*1024
    float* mW0T    = fwinzT  + 4 * 1024;               // 2048
    float* fpw     = mW0T    + 2048;                   // 4*49152
    float* mpw     = fpw     + 4 * 49152;              // 49152
    float* fpb     = mpw     + 49152;                  // 4*384
    float* mpb     = fpb     + 4 * 384;                // 384
    f16*   fW1f    = (f16*)(mpb + 384);                // 8*16384 f16
    f16*   fW2f    = fW1f    + 8 * 16384;              // 8*16384
    f16*   mW1f    = fW2f    + 8 * 16384;              // 2*16384
    f16*   mW2f    = mW1f    + 2 * 16384;              // 2*16384
    f16*   fWoutf  = mW2f    + 2 * 16384;              // 4*24576
    f16*   mWoutf  = fWoutf  + 4 * 24576;              // 4096

    dim3 B(256);
    pack_kernel<<<dim3(768, 12), B, 0, stream>>>(
        sp_bW1, sp_bW2, made_bW1, made_bW2, sp_Wout, made_Wout, sp_Win, made_W0,
        sp_bCW, made_ctxW, made_bCW, sp_bin, sp_bCb, made_ctxb, made_b0, made_bCb,
        fW1f, fW2f, mW1f, mW2f, fWoutf, mWoutf, fwinzT, mW0T, fpw, mpw, fpb, mpb);
    ctx_kernel<<<4608, B, 0, stream>>>(ctx);
    snorm_kernel<<<2304, B, 0, stream>>>(x, z);
    initlogq_kernel<<<144, B, 0, stream>>>(lu_udiag, logq);

    for (int i = 3; i >= 0; --i) {
        lu_kernel<<<144, B, 0, stream>>>(z, lu_lower + i * 256, lu_upper + i * 256,
                                         lu_udiag + i * 16, lu_bias + i * 16, lu_perm + i * 16);
        gemm_k<4><<<dim3(144, 6), B, 0, stream>>>(ctx, 128, fpw + (size_t)i * 49152, 128,
                                                  fpb + i * 384, ctxout, 384, NHW, 384, 128);
        mega_mfma<0><<<576, B, 0, stream>>>(z, ctxout, fwinzT + i * 1024,
                                            fW1f + (size_t)i * 32768, fW2f + (size_t)i * 32768,
                                            sp_bb1 + i * 256, sp_bb2 + i * 256,
                                            fWoutf + (size_t)i * 24576, sp_bout + i * 184, p);
        spline_kernel<<<1152, B, 0, stream>>>(z, p, sp_uw + i * 64, sp_uh + i * 64, sp_ud + i * 56, logq);
    }

    // ---- MADE ----
    gemm_k<4><<<dim3(144, 6), B, 0, stream>>>(ctx, 128, mpw, 128, mpb, ctxout, 384, NHW, 384, 128);
    mega_mfma<1><<<576, B, 0, stream>>>(z, ctxout, mW0T, mW1f, mW2f,
                                        made_bb1, made_bb2, mWoutf, made_bout, p);
    made_out_kernel<<<144, B, 0, stream>>>(p, z, logq);

    // ---- encoder (per-hw) ----
    gemm_k<2><<<dim3(144, 2), B, 0, stream>>>(ctx, 128, enc_W1, 128, enc_b1, thw_enc, 128, NHW, 128, 128);
    gemm_k<0><<<dim3(144, 1), B, 0, stream>>>(thw_enc, 128, enc_W2, 128, enc_b2, ehw, 32, NHW, 32, 128);
    final_kernel<<<144, B, 0, stream>>>(z, ehw, logq, out);
}